// Round 7
// baseline (493.217 us; speedup 1.0000x reference)
//
#include <hip/hip_runtime.h>
#include <hip/hip_bf16.h>
#include <stdint.h>

// Swin-3D window attention, fused. B=4096 windows, N=64 tokens, C=96, H=8, hd=12.
// R7: PERSISTENT blocks. Grid 512 (2/CU resident), each block loops 8 windows
// strided by 512 (wmask const per block -> biasm slice + weights L2/L1-hot).
// Next-window X prefetched into regs under the attention phase; wprojT frags
// hoisted under barrier 2. 512 thr / 8 waves, one head per wave, LDS 51200 B.
//
// ws layout (bytes):
//   [0, 8388608)            biasm fp32 [64 w][8 h][64 q][64 m]  ((bias+mask)*log2e)
//   [8388608, +55296)       wqkv  bf16 [288][96]  (Q rows pre-scaled by hd^-0.5*log2e)
//   [8443904, +24576)       wprojT bf16 [8 h][96 o][16 c]  (chans 12..15 zero)

typedef float  f32x4  __attribute__((ext_vector_type(4)));
typedef float  f32x16 __attribute__((ext_vector_type(16)));
typedef short  short8 __attribute__((ext_vector_type(8)));

#define WS_WQKV_OFF   (8388608)
#define WS_WPROJT_OFF (8388608 + 55296)
#define LOG2E 1.4426950408889634f

__device__ __forceinline__ unsigned short f2bf(float f) {
  __hip_bfloat16 h = __float2bfloat16(f);
  return *reinterpret_cast<unsigned short*>(&h);
}
__device__ __forceinline__ uint32_t pack2(float a, float b) {
  __hip_bfloat162 h = __float22bfloat162_rn(float2{a, b});
  return *reinterpret_cast<uint32_t*>(&h);
}

__global__ void prep_weights(const float* __restrict__ qkv_w,
                             const float* __restrict__ proj_w,
                             unsigned short* __restrict__ ws16) {
  int tid = blockIdx.x * 256 + threadIdx.x;          // 156 blocks * 256 = 39936 exact
  if (tid < 27648) {
    float v = qkv_w[tid];
    if (tid < 9216) v *= (0.28867513459481288f * LOG2E);  // SCALE*log2e into Q rows
    ws16[WS_WQKV_OFF / 2 + tid] = f2bf(v);
  } else {
    int t = tid - 27648;                             // < 12288 = 8*96*16
    int h = t / 1536, rem = t - h * 1536;
    int o = rem >> 4, c = rem & 15;
    float v = (c < 12) ? proj_w[o * 96 + h * 12 + c] : 0.f;
    ws16[WS_WPROJT_OFF / 2 + t] = f2bf(v);
  }
}

// biasm[w][h][q=r][key=m] = (bias_table[relidx(r,m)][h] + mask[w][r][m]) * log2e
__global__ void prep_biasm(const float* __restrict__ mask,
                           const float* __restrict__ bias_table,
                           float* __restrict__ biasm) {
  int tid = blockIdx.x * 256 + threadIdx.x;          // 8192 blocks * 256 = 2097152 exact
  int m = tid & 63;            // key (inner)
  int r = (tid >> 6) & 63;     // query
  int h = (tid >> 12) & 7;
  int w = tid >> 15;
  int dr = r >> 4, hr = (r >> 2) & 3, wr = r & 3;
  int dm = m >> 4, hm = (m >> 2) & 3, wm = m & 3;
  int idx = (dr - dm + 3) * 49 + (hr - hm + 3) * 7 + (wr - wm + 3);
  biasm[tid] = (bias_table[idx * 8 + h] + mask[(w * 64 + r) * 64 + m]) * LOG2E;
}

__global__ __launch_bounds__(512, 4) void attn_main(
    const float* __restrict__ x, const float* __restrict__ proj_b,
    const unsigned short* __restrict__ ws16, const float* __restrict__ biasm,
    float* __restrict__ out) {
  // 51200 B total LDS -> 2 blocks/CU
  __shared__ __align__(16) unsigned short q_s[8][64][16];  // Q then O^T overlay (per head)
  __shared__ __align__(16) unsigned short k_s[8][64][16];
  __shared__ __align__(16) unsigned short v_s[8][16][72];  // chan-major

  const int tid  = threadIdx.x;
  const int wv   = tid >> 6;          // 0..7
  const int lane = tid & 63;
  const int lo4 = lane & 15, hi4 = lane >> 4;
  const int lo5 = lane & 31, hi5 = lane >> 5;
  const int blk = blockIdx.x;         // 0..511
  const int wmask = blk & 63;         // constant per block (512 % 64 == 0)

  const unsigned short* wqkv   = ws16 + WS_WQKV_OFF / 2;
  const unsigned short* wprojT = ws16 + WS_WPROJT_OFF / 2;

  // --- zero pad chans 12..15 of q_s/k_s once (never overwritten) ---
  {
    int h = tid >> 6, r = tid & 63;
    *(uint2*)&q_s[h][r][12] = make_uint2(0u, 0u);
    *(uint2*)&k_s[h][r][12] = make_uint2(0u, 0u);
  }

  const int sub = wv & 3;           // token tile (16 tokens)
  const int par = wv >> 2;          // M-tile parity
  const int trow = sub * 16 + lo4;  // this lane's token
  const int mt3 = wv >> 1;          // GEMM3 M-tile
  const int nb3 = (wv & 1) * 3;     // GEMM3 first N-tile
  const int arow3 = mt3 * 16 + lo4;
  const int hh3 = hi4 >> 1;
  const int off8 = (hi4 & 1) * 8;

  // --- prefetch X for window 0 ---
  float4 xa[6];
  {
    const float* xrow = x + (size_t)blk * 6144 + (size_t)trow * 96;
#pragma unroll
    for (int ks = 0; ks < 3; ++ks) {
      xa[2 * ks]     = *(const float4*)&xrow[ks * 32 + hi4 * 8];
      xa[2 * ks + 1] = *(const float4*)&xrow[ks * 32 + hi4 * 8 + 4];
    }
  }

  for (int it = 0; it < 8; ++it) {
    const int win = (it << 9) | blk;

    // --- pack X frags (frees xa for the next prefetch) ---
    short8 bfX[3];
#pragma unroll
    for (int ks = 0; ks < 3; ++ks) {
      union { uint32_t u[4]; short8 s; } t;
      t.u[0] = pack2(xa[2 * ks].x,     xa[2 * ks].y);
      t.u[1] = pack2(xa[2 * ks].z,     xa[2 * ks].w);
      t.u[2] = pack2(xa[2 * ks + 1].x, xa[2 * ks + 1].y);
      t.u[3] = pack2(xa[2 * ks + 1].z, xa[2 * ks + 1].w);
      bfX[ks] = t.s;
    }

    // --- GEMM1 (transposed): QKV^T = Wqkv @ X^T ---
    {
      f32x4 acc[9];
#pragma unroll
      for (int i = 0; i < 9; ++i) acc[i] = (f32x4){0.f, 0.f, 0.f, 0.f};
#pragma unroll
      for (int ks = 0; ks < 3; ++ks) {
#pragma unroll
        for (int i = 0; i < 9; ++i) {
          const int mt = 2 * i + par;
          short8 afW = *(const short8*)&wqkv[(mt * 16 + lo4) * 96 + ks * 32 + hi4 * 8];
          acc[i] = __builtin_amdgcn_mfma_f32_16x16x32_bf16(afW, bfX[ks], acc[i], 0, 0, 0);
        }
      }
      // scatter: Q/K one b64 per tile, V 4 scalar (chan-major)
#pragma unroll
      for (int i = 0; i < 9; ++i) {
        const int mt = 2 * i + par;
        const int o0 = mt * 16 + hi4 * 4;
        if (o0 < 192) {
          const int sec = (o0 >= 96) ? 96 : 0;
          const int o = o0 - sec;
          const int head = o / 12, ch = o - head * 12;   // ch in {0,4,8}
          uint2 w2;
          w2.x = pack2(acc[i][0], acc[i][1]);
          w2.y = pack2(acc[i][2], acc[i][3]);
          if (sec == 0) *(uint2*)&q_s[head][trow][ch] = w2;
          else          *(uint2*)&k_s[head][trow][ch] = w2;
        } else {
          const int o = o0 - 192;
          const int head = o / 12, ch = o - head * 12;
#pragma unroll
          for (int j = 0; j < 4; ++j)
            v_s[head][ch + j][trow] = f2bf(acc[i][j]);
        }
      }
    }

    // --- prefetch next window's X (in flight under bias+barrier+attention) ---
    if (it < 7) {
      const float* xrow = x + (size_t)(win + 512) * 6144 + (size_t)trow * 96;
#pragma unroll
      for (int ks = 0; ks < 3; ++ks) {
        xa[2 * ks]     = *(const float4*)&xrow[ks * 32 + hi4 * 8];
        xa[2 * ks + 1] = *(const float4*)&xrow[ks * 32 + hi4 * 8 + 4];
      }
    }

    // --- bias+mask c-init (L2-hot after window 0), drains under barrier 1 ---
    f32x16 c[2][2];
    {
      const float* bm = biasm + (size_t)(wmask * 8 + wv) * 4096;
#pragma unroll
      for (int ti = 0; ti < 2; ++ti)
#pragma unroll
        for (int tj = 0; tj < 2; ++tj)
#pragma unroll
          for (int q4 = 0; q4 < 4; ++q4) {
            float4 b4 = *(const float4*)&bm[(tj * 32 + lo5) * 64 + ti * 32 + 8 * q4 + 4 * hi5];
            c[ti][tj][4 * q4 + 0] = b4.x;
            c[ti][tj][4 * q4 + 1] = b4.y;
            c[ti][tj][4 * q4 + 2] = b4.z;
            c[ti][tj][4 * q4 + 3] = b4.w;
          }
    }
    __syncthreads();   // barrier 1: q/k/v staged

    // --- attention: wave wv = head wv (S^T and softmax in exp2 domain) ---
    f32x16 oD[2];
    {
      const int h = wv;
      __builtin_amdgcn_s_setprio(1);
#pragma unroll
      for (int ti = 0; ti < 2; ++ti) {
        short8 af = *(const short8*)&k_s[h][ti * 32 + lo5][hi5 * 8];
#pragma unroll
        for (int tj = 0; tj < 2; ++tj) {
          short8 bf = *(const short8*)&q_s[h][tj * 32 + lo5][hi5 * 8];
          c[ti][tj] = __builtin_amdgcn_mfma_f32_32x32x16_bf16(af, bf, c[ti][tj], 0, 0, 0);
        }
      }
      __builtin_amdgcn_s_setprio(0);

      // softmax over m: lane holds 32 of 64 m per q; partner lane^32
#pragma unroll
      for (int tj = 0; tj < 2; ++tj) {
        float mx = -1e30f;
#pragma unroll
        for (int ti = 0; ti < 2; ++ti)
#pragma unroll
          for (int reg = 0; reg < 16; ++reg) mx = fmaxf(mx, c[ti][tj][reg]);
        mx = fmaxf(mx, __shfl_xor(mx, 32));
        float sum = 0.f;
#pragma unroll
        for (int ti = 0; ti < 2; ++ti)
#pragma unroll
          for (int reg = 0; reg < 16; ++reg) {
            float e = exp2f(c[ti][tj][reg] - mx);
            c[ti][tj][reg] = e;
            sum += e;
          }
        sum += __shfl_xor(sum, 32);
        float rs = 1.0f / sum;
#pragma unroll
        for (int ti = 0; ti < 2; ++ti)
#pragma unroll
          for (int reg = 0; reg < 16; ++reg) c[ti][tj][reg] *= rs;
      }

      // pack P^T to bf16 pairs
      uint32_t pkp[2][2][8];
#pragma unroll
      for (int ti = 0; ti < 2; ++ti)
#pragma unroll
        for (int tj = 0; tj < 2; ++tj)
#pragma unroll
          for (int u = 0; u < 8; ++u)
            pkp[ti][tj][u] = pack2(c[ti][tj][2 * u], c[ti][tj][2 * u + 1]);

      // PV: O^T = V^T @ P^T; B assembled in-register (partner via lane^32)
      oD[0] = (f32x16)(0.f); oD[1] = (f32x16)(0.f);
#pragma unroll
      for (int kc = 0; kc < 4; ++kc) {
        const int ti = kc >> 1, base = 4 * (kc & 1);
        short8 av = *(const short8*)&v_s[h][lo5 & 15][kc * 16 + hi5 * 8];
#pragma unroll
        for (int tj = 0; tj < 2; ++tj) {
          uint32_t A0 = pkp[ti][tj][base + 0], A1 = pkp[ti][tj][base + 1];
          uint32_t A2 = pkp[ti][tj][base + 2], A3 = pkp[ti][tj][base + 3];
          uint32_t k0 = hi5 ? A2 : A0, k1 = hi5 ? A3 : A1;
          uint32_t s0 = (uint32_t)__shfl_xor((int)(hi5 ? A0 : A2), 32);
          uint32_t s1 = (uint32_t)__shfl_xor((int)(hi5 ? A1 : A3), 32);
          union { uint32_t u[4]; short8 s; } bfr;
          bfr.u[0] = hi5 ? s0 : k0;
          bfr.u[1] = hi5 ? s1 : k1;
          bfr.u[2] = hi5 ? k0 : s0;
          bfr.u[3] = hi5 ? k1 : s1;
          __builtin_amdgcn_s_setprio(1);
          oD[tj] = __builtin_amdgcn_mfma_f32_32x32x16_bf16(av, bfr.s, oD[tj], 0, 0, 0);
          __builtin_amdgcn_s_setprio(0);
        }
      }
    }

    // --- hoist GEMM3 B-frags (independent of O; drain under barrier 2) ---
    short8 wf[12];
#pragma unroll
    for (int ks = 0; ks < 4; ++ks)
#pragma unroll
      for (int nt = 0; nt < 3; ++nt)
        wf[ks * 3 + nt] = *(const short8*)
            &wprojT[((size_t)(ks * 2 + hh3) * 96 + (nb3 + nt) * 16 + lo4) * 16 + off8];

    // --- O^T -> overlay q_s[h] (own wave; DS ops wave-ordered, no sync) ---
    {
      const int h = wv;
#pragma unroll
      for (int tj = 0; tj < 2; ++tj) {
        const int q = tj * 32 + lo5;
        uint2 w2;
        w2.x = pack2(oD[tj][0], oD[tj][1]);
        w2.y = pack2(oD[tj][2], oD[tj][3]);
        *(uint2*)&q_s[h][q][4 * hi5] = w2;
        if (hi5 == 0) {
          uint2 w3;
          w3.x = pack2(oD[tj][4], oD[tj][5]);
          w3.y = pack2(oD[tj][6], oD[tj][7]);
          *(uint2*)&q_s[h][q][8] = w3;
        }
      }
    }
    __syncthreads();   // barrier 2: all heads' O in q_s

    // --- GEMM3: OUT = O @ Wproj^T + b, K=128 zero-padded ---
    {
      f32x4 acc[3];
#pragma unroll
      for (int nt = 0; nt < 3; ++nt) acc[nt] = (f32x4){0.f, 0.f, 0.f, 0.f};
#pragma unroll
      for (int ks = 0; ks < 4; ++ks) {
        short8 af = *(const short8*)&q_s[ks * 2 + hh3][arow3][off8];
#pragma unroll
        for (int nt = 0; nt < 3; ++nt)
          acc[nt] = __builtin_amdgcn_mfma_f32_16x16x32_bf16(af, wf[ks * 3 + nt], acc[nt], 0, 0, 0);
      }
      float* od = out + (size_t)win * 6144;
#pragma unroll
      for (int nt = 0; nt < 3; ++nt) {
        const int ntg = nb3 + nt;
        float pb = proj_b[ntg * 16 + lo4];
#pragma unroll
        for (int j = 0; j < 4; ++j)
          od[(mt3 * 16 + hi4 * 4 + j) * 96 + ntg * 16 + lo4] = acc[nt][j] + pb;
      }
    }
    __syncthreads();   // barrier 3: GEMM3 reads done before next scatter
  }
}

extern "C" void kernel_launch(void* const* d_in, const int* in_sizes, int n_in,
                              void* d_out, int out_size, void* d_ws, size_t ws_size,
                              hipStream_t stream) {
  const float* x          = (const float*)d_in[0];
  const float* mask       = (const float*)d_in[1];
  const float* qkv_w      = (const float*)d_in[2];
  const float* proj_w     = (const float*)d_in[3];
  const float* proj_b     = (const float*)d_in[4];
  const float* bias_table = (const float*)d_in[5];

  float* biasm = (float*)d_ws;
  unsigned short* ws16 = (unsigned short*)d_ws;

  prep_weights<<<156, 256, 0, stream>>>(qkv_w, proj_w, ws16);
  prep_biasm<<<8192, 256, 0, stream>>>(mask, bias_table, biasm);
  attn_main<<<512, 512, 0, stream>>>(x, proj_b, ws16, biasm, (float*)d_out);
}

// Round 9
// 193.095 us; speedup vs baseline: 2.5543x; 2.5543x over previous
//
#include <hip/hip_runtime.h>
#include <stdint.h>

// Swin-3D window attention, fused. B=4096 windows, N=64 tokens, C=96, H=8, hd=12.
// R8b: wave-private front end (R8 with __fp16 types fixed). Per-head PADDED
// weights (12 rows -> 16-row M-tile) make GEMM1 D-frags directly usable as
// 16x16x16f16 QK operands, and S^T D-frags directly usable as PV A-operands.
// No LDS/barrier for Q/K/P; V via wave-private LDS transpose (no sync); O via
// LDS with ONE barrier for the cross-head proj. f16 arithmetic everywhere.
// 512 thr / 8 waves, one head per wave, 1 win/block.
//
// ws layout (bytes):
//   [0, 8388608)            biasm fp32 [64 w][8 h][64 q][64 m]  ((bias+mask)*log2e)
//   [8388608, +73728)       wqkvP f16 [8 h][3 s][16 r][96 c] (r>=12 zero;
//                                     s=0 rows pre-scaled by hd^-0.5*log2e)
//   [8462336, +24576)       wprojT f16 [8 h][96 o][16 c]  (c 12..15 zero)

typedef float  f32x4  __attribute__((ext_vector_type(4)));
typedef __fp16 f16x2  __attribute__((ext_vector_type(2)));
typedef __fp16 f16x4  __attribute__((ext_vector_type(4)));
typedef __fp16 f16x8  __attribute__((ext_vector_type(8)));

#define WS_WQKVP_OFF  (8388608)
#define WS_WPROJT_OFF (8388608 + 73728)
#define LOG2E 1.4426950408889634f

__device__ __forceinline__ f16x4 pk4(f32x4 v) {
  union { f16x2 p[2]; f16x4 v; } u;
  u.p[0] = __builtin_amdgcn_cvt_pkrtz(v[0], v[1]);
  u.p[1] = __builtin_amdgcn_cvt_pkrtz(v[2], v[3]);
  return u.v;
}

__global__ void prep_weights(const float* __restrict__ qkv_w,
                             const float* __restrict__ proj_w,
                             __fp16* __restrict__ wsh) {
  int tid = blockIdx.x * 256 + threadIdx.x;          // 192 blocks * 256 = 49152 exact
  if (tid < 36864) {                                 // wqkvP [8][3][16][96]
    int h = tid / 4608, rem = tid - h * 4608;
    int s = rem / 1536, rem2 = rem - s * 1536;
    int r = rem2 / 96, cc = rem2 - r * 96;
    float v = 0.f;
    if (r < 12) {
      v = qkv_w[(s * 96 + h * 12 + r) * 96 + cc];
      if (s == 0) v *= (0.28867513459481288f * LOG2E);
    }
    wsh[WS_WQKVP_OFF / 2 + tid] = (__fp16)v;
  } else {                                           // wprojT [8][96][16]
    int t = tid - 36864;                             // < 12288
    int h = t / 1536, rem = t - h * 1536;
    int o = rem >> 4, c = rem & 15;
    float v = (c < 12) ? proj_w[o * 96 + h * 12 + c] : 0.f;
    wsh[WS_WPROJT_OFF / 2 + t] = (__fp16)v;
  }
}

// biasm[w][h][q=r][key=m] = (bias_table[relidx(r,m)][h] + mask[w][r][m]) * log2e
__global__ void prep_biasm(const float* __restrict__ mask,
                           const float* __restrict__ bias_table,
                           float* __restrict__ biasm) {
  int tid = blockIdx.x * 256 + threadIdx.x;          // 8192 blocks * 256 = 2097152 exact
  int m = tid & 63;            // key (inner)
  int r = (tid >> 6) & 63;     // query
  int h = (tid >> 12) & 7;
  int w = tid >> 15;
  int dr = r >> 4, hr = (r >> 2) & 3, wr = r & 3;
  int dm = m >> 4, hm = (m >> 2) & 3, wm = m & 3;
  int idx = (dr - dm + 3) * 49 + (hr - hm + 3) * 7 + (wr - wm + 3);
  biasm[tid] = (bias_table[idx * 8 + h] + mask[(w * 64 + r) * 64 + m]) * LOG2E;
}

__global__ __launch_bounds__(512, 4) void attn_main(
    const float* __restrict__ x, const float* __restrict__ proj_b,
    const __fp16* __restrict__ wsh, const float* __restrict__ biasm,
    float* __restrict__ out) {
  // LDS: v 8*16*68*2 = 34816 B, o 8*64*24*2 = 24576 B -> 59392 B, 2 blocks/CU
  __shared__ __fp16 v_lds[8][16][68];   // per-wave V^T [chan][tok], padded
  __shared__ __fp16 o_lds[8][64][24];   // per-head O [tok][16 chan], row 48B

  const int tid  = threadIdx.x;
  const int wv   = tid >> 6;          // 0..7 = head
  const int lane = tid & 63;
  const int lo4 = lane & 15, hi4 = lane >> 4;
  const int blk = blockIdx.x;
  const int wmask = blk & 63;

  const __fp16* wq  = wsh + WS_WQKVP_OFF / 2 + wv * (3 * 16 * 96);
  const __fp16* wpT = wsh + WS_WPROJT_OFF / 2;

  // --- GEMM1: per-head QKV^T = WqkvP[h] @ X^T. D[o-chan][token] per 16x16 tile.
  //     A = W rows (lane=o-chan, k=x-chan), B = X^T (lane=token, k=x-chan). ---
  f32x4 a1[3][4];                     // [s=q,k,v][token-tile]
#pragma unroll
  for (int s = 0; s < 3; ++s)
#pragma unroll
    for (int tt = 0; tt < 4; ++tt) a1[s][tt] = (f32x4){0.f, 0.f, 0.f, 0.f};
  {
    const float* xw = x + (size_t)blk * 6144;
#pragma unroll
    for (int ks = 0; ks < 3; ++ks) {
      f16x8 bx[4];
#pragma unroll
      for (int tt = 0; tt < 4; ++tt) {
        const float* p = &xw[(tt * 16 + lo4) * 96 + ks * 32 + hi4 * 8];
        float4 v0 = *(const float4*)p;
        float4 v1 = *(const float4*)(p + 4);
        union { f16x2 h2[4]; f16x8 v; } u;
        u.h2[0] = __builtin_amdgcn_cvt_pkrtz(v0.x, v0.y);
        u.h2[1] = __builtin_amdgcn_cvt_pkrtz(v0.z, v0.w);
        u.h2[2] = __builtin_amdgcn_cvt_pkrtz(v1.x, v1.y);
        u.h2[3] = __builtin_amdgcn_cvt_pkrtz(v1.z, v1.w);
        bx[tt] = u.v;
      }
#pragma unroll
      for (int s = 0; s < 3; ++s) {
        f16x8 aw = *(const f16x8*)&wq[(s * 16 + lo4) * 96 + ks * 32 + hi4 * 8];
#pragma unroll
        for (int tt = 0; tt < 4; ++tt)
          a1[s][tt] = __builtin_amdgcn_mfma_f32_16x16x32_f16(aw, bx[tt], a1[s][tt], 0, 0, 0);
      }
    }
  }

  // --- Q/K frags in-register (D-frag IS the 16x16x16 operand frag);
  //     V to wave-private LDS transpose (no sync: same-wave DS ordering) ---
  f16x4 Qf[4], Kf[4];
#pragma unroll
  for (int tt = 0; tt < 4; ++tt) {
    Qf[tt] = pk4(a1[0][tt]);
    Kf[tt] = pk4(a1[1][tt]);
#pragma unroll
    for (int j = 0; j < 4; ++j)
      v_lds[wv][hi4 * 4 + j][tt * 16 + lo4] = (__fp16)a1[2][tt][j];
  }

  // --- bias+mask c-init: c[mt][qt], reg j = m = mt*16 + hi4*4 + j ---
  f32x4 c[4][4];
  {
    const float* bm = biasm + (size_t)(wmask * 8 + wv) * 4096;
#pragma unroll
    for (int qt = 0; qt < 4; ++qt)
#pragma unroll
      for (int mt = 0; mt < 4; ++mt)
        c[mt][qt] = *(const f32x4*)&bm[(qt * 16 + lo4) * 64 + mt * 16 + hi4 * 4];
  }

  // --- S^T = K @ Q^T via 16x16x16f16 (K dim = 16 chans, 12 real + 4 zero) ---
  __builtin_amdgcn_s_setprio(1);
#pragma unroll
  for (int mt = 0; mt < 4; ++mt)
#pragma unroll
    for (int qt = 0; qt < 4; ++qt)
      c[mt][qt] = __builtin_amdgcn_mfma_f32_16x16x16f16(Kf[mt], Qf[qt], c[mt][qt], 0, 0, 0);
  __builtin_amdgcn_s_setprio(0);

  // --- softmax over m (rows): lane has 16 m's (4 mt x 4 reg) for q = qt*16+lo4;
  //     partners at lane^16, lane^32 hold the other m-quads ---
#pragma unroll
  for (int qt = 0; qt < 4; ++qt) {
    float mx = -1e30f;
#pragma unroll
    for (int mt = 0; mt < 4; ++mt)
#pragma unroll
      for (int j = 0; j < 4; ++j) mx = fmaxf(mx, c[mt][qt][j]);
    mx = fmaxf(mx, __shfl_xor(mx, 16));
    mx = fmaxf(mx, __shfl_xor(mx, 32));
    float sum = 0.f;
#pragma unroll
    for (int mt = 0; mt < 4; ++mt)
#pragma unroll
      for (int j = 0; j < 4; ++j) {
        float e = exp2f(c[mt][qt][j] - mx);
        c[mt][qt][j] = e;
        sum += e;
      }
    sum += __shfl_xor(sum, 16);
    sum += __shfl_xor(sum, 32);
    float rs = 1.0f / sum;
#pragma unroll
    for (int mt = 0; mt < 4; ++mt)
#pragma unroll
      for (int j = 0; j < 4; ++j) c[mt][qt][j] *= rs;
  }

  // --- P frags (S^T D-frag IS the PV A-frag) + V B-frags from LDS ---
  f16x4 pa[4][4];                     // [qt][mt]
#pragma unroll
  for (int qt = 0; qt < 4; ++qt)
#pragma unroll
    for (int mt = 0; mt < 4; ++mt) pa[qt][mt] = pk4(c[mt][qt]);
  f16x4 vb[4];
#pragma unroll
  for (int mt = 0; mt < 4; ++mt)
    vb[mt] = *(const f16x4*)&v_lds[wv][lo4][mt * 16 + hi4 * 4];

  // --- PV: O = P @ V (A lane=q, k=m; B lane=chan, k=m). D: col=chan, row=q ---
  f32x4 o4[4];
#pragma unroll
  for (int qt = 0; qt < 4; ++qt) o4[qt] = (f32x4){0.f, 0.f, 0.f, 0.f};
  __builtin_amdgcn_s_setprio(1);
#pragma unroll
  for (int mt = 0; mt < 4; ++mt)
#pragma unroll
    for (int qt = 0; qt < 4; ++qt)
      o4[qt] = __builtin_amdgcn_mfma_f32_16x16x16f16(pa[qt][mt], vb[mt], o4[qt], 0, 0, 0);
  __builtin_amdgcn_s_setprio(0);

  // --- GEMM3 B-frags prefetch (independent of O; drain under the barrier) ---
  const int mt3 = wv >> 1;            // M-tile 0..3
  const int nb3 = (wv & 1) * 3;       // first N-tile
  const int arow3 = mt3 * 16 + lo4;
  const int hh3 = hi4 >> 1;
  const int off8 = (hi4 & 1) * 8;
  f16x8 wf[12];
#pragma unroll
  for (int ks = 0; ks < 4; ++ks)
#pragma unroll
    for (int nt = 0; nt < 3; ++nt)
      wf[ks * 3 + nt] = *(const f16x8*)
          &wpT[((size_t)(ks * 2 + hh3) * 96 + (nb3 + nt) * 16 + lo4) * 16 + off8];

  // --- O -> o_lds[h][tok][chan] (chans 12..15 auto-zero via V zero rows) ---
#pragma unroll
  for (int qt = 0; qt < 4; ++qt)
#pragma unroll
    for (int j = 0; j < 4; ++j)
      o_lds[wv][qt * 16 + hi4 * 4 + j][lo4] = (__fp16)o4[qt][j];

  __syncthreads();   // the ONLY barrier: all heads' O visible

  // --- GEMM3: OUT = O @ Wproj^T + b, K=128 zero-padded (8 heads x 16 chans) ---
  {
    f32x4 acc[3];
#pragma unroll
    for (int nt = 0; nt < 3; ++nt) acc[nt] = (f32x4){0.f, 0.f, 0.f, 0.f};
#pragma unroll
    for (int ks = 0; ks < 4; ++ks) {
      f16x8 af = *(const f16x8*)&o_lds[ks * 2 + hh3][arow3][off8];
#pragma unroll
      for (int nt = 0; nt < 3; ++nt)
        acc[nt] = __builtin_amdgcn_mfma_f32_16x16x32_f16(af, wf[ks * 3 + nt], acc[nt], 0, 0, 0);
    }
    float* od = out + (size_t)blk * 6144;
#pragma unroll
    for (int nt = 0; nt < 3; ++nt) {
      const int ntg = nb3 + nt;
      float pb = proj_b[ntg * 16 + lo4];
#pragma unroll
      for (int j = 0; j < 4; ++j)
        od[(mt3 * 16 + hi4 * 4 + j) * 96 + ntg * 16 + lo4] = acc[nt][j] + pb;
    }
  }
}

extern "C" void kernel_launch(void* const* d_in, const int* in_sizes, int n_in,
                              void* d_out, int out_size, void* d_ws, size_t ws_size,
                              hipStream_t stream) {
  const float* x          = (const float*)d_in[0];
  const float* mask       = (const float*)d_in[1];
  const float* qkv_w      = (const float*)d_in[2];
  const float* proj_w     = (const float*)d_in[3];
  const float* proj_b     = (const float*)d_in[4];
  const float* bias_table = (const float*)d_in[5];

  float* biasm = (float*)d_ws;
  __fp16* wsh = (__fp16*)d_ws;

  prep_weights<<<192, 256, 0, stream>>>(qkv_w, proj_w, wsh);
  prep_biasm<<<8192, 256, 0, stream>>>(mask, bias_table, biasm);
  attn_main<<<4096, 512, 0, stream>>>(x, proj_b, wsh, biasm, (float*)d_out);
}